// Round 10
// baseline (21178.368 us; speedup 1.0000x reference)
//
#include <hip/hip_runtime.h>

// ---------------------------------------------------------------------------
// OmniAnomaly forward, round 10: barrier-free dataflow pipeline.
// Roles: QG (GRU-q) 64 WGs [slab 16 rows x 256-col slice], QA (lin+heads+flows)
// 32 WGs [slab x half], PG 64, PA 32. Producer->consumer flags (relaxed agent,
// monotonic). Cross-WG WRITES: uncached agent-scope (-> MALL). Cross-WG READS:
// plain cached at per-t-unique addresses (big mode, ws>=200MB) or uncached
// depth-4 (small mode). No fences, no global barriers.
// B=256, W=128, IN=128, H=1024, Z=128, D=1024, OUT=128, K=3 flows
// ---------------------------------------------------------------------------

typedef __bf16 bf16;
typedef __bf16 bf16x8 __attribute__((ext_vector_type(8)));
typedef float  f32x4  __attribute__((ext_vector_type(4)));
typedef unsigned long long u64;
typedef unsigned u32;

static constexpr int CB   = 256;
static constexpr int CW   = 128;
static constexpr int CIN  = 128;
static constexpr int CH   = 1024;
static constexpr int CZ   = 128;
static constexpr int CD   = 1024;
static constexpr int COUT = 128;
static constexpr int APITCH = 1160;    // 1152 + 8 pad

// flag table: index*16 u32 spacing (64B)
static constexpr int FS   = 16;
static constexpr int FQG  = 0;    // 64
static constexpr int FQAa = 64;   // 16
static constexpr int FQAb = 80;   // 16
static constexpr int FQAd = 96;   // 32
static constexpr int FPG  = 128;  // 64
static constexpr int FPAa = 192;  // 16
static constexpr int FPAb = 208;  // 16
static constexpr int FPAd = 224;  // 32
static constexpr int NFLAG = 256;

#define DEV static __device__ __forceinline__

DEV float sigmoidf_(float x) { return 1.0f / (1.0f + expf(-x)); }
DEV float softplusf_(float x) { return x > 20.0f ? x : log1pf(expf(x)); }
DEV bf16x8 ldfrag(const bf16* p) { return *reinterpret_cast<const bf16x8*>(p); }

#define MFMA(a, b, c) __builtin_amdgcn_mfma_f32_16x16x32_bf16((a), (b), (c), 0, 0, 0)

DEV u64 lda8(const void* p) {
    return __hip_atomic_load((const u64*)p, __ATOMIC_RELAXED, __HIP_MEMORY_SCOPE_AGENT);
}
DEV u32 lda4(const void* p) {
    return __hip_atomic_load((const u32*)p, __ATOMIC_RELAXED, __HIP_MEMORY_SCOPE_AGENT);
}
DEV void sta4(void* p, u32 v) {
    __hip_atomic_store((u32*)p, v, __ATOMIC_RELAXED, __HIP_MEMORY_SCOPE_AGENT);
}
DEV bf16x8 ld_act16(const bf16* p) {
    union { u64 u[2]; bf16x8 v; } r;
    r.u[0] = lda8(p);
    r.u[1] = lda8((const char*)p + 8);
    return r.v;
}
DEV u32 pk2(float a, float b) {
    union { bf16 h[2]; u32 u; } r;
    r.h[0] = (bf16)a; r.h[1] = (bf16)b;
    return r.u;
}
DEV void poll_ge(const u32* f, int tgt) {
    if (tgt <= 0) return;
    while ((int)lda4(f) < tgt) __builtin_amdgcn_s_sleep(2);
}

struct Prm {
    const float *eps_q, *eps_p;
    const float *bih_q, *bhh_q, *bd_q, *bmu_q, *bsig_q;
    const float *Wp, *bp, *up, *Wlg, *blg;
    const float *bih_p, *bhh_p, *bd_p, *bmu_p, *bsig_p;
    const bf16 *x_b, *Wih_qb, *Whh_qb, *Wd_qb, *Wmu_qb, *Wsg_qb;
    const bf16 *Wih_pb, *Whh_pb, *Wd_pb, *Wmu_pb, *Wsg_pb;
    float *ef, *df;                 // fp32 masters [2][CB][CH] (WG-col-private)
    bf16 *e_h, *d_h;                // history [DE][CB][CH]
    bf16 *dvpp, *ddvpp;             // [2][CB][CD] (uncached rw)
    bf16 *ztlg;                     // [CW][CB][CZ] (uncached w, cached r)
    bf16 *zfl;                      // [4][CB][CZ] (uncached rw)
    float *shq, *shp;               // [2][CB][CZ] f32 (uncached rw)
    u32 *F;
    float *out_o, *out_mu, *out_lv;
    int DEm;                        // DE-1 (DE power of 2)
    int big;                        // 1: cached history reads
};

// ---------------------------------------------------------------------------
__global__ void k_cvt(const float* __restrict__ src, bf16* __restrict__ dst, int n)
{
    int i = (blockIdx.x * blockDim.x + threadIdx.x) * 4;
    if (i < n) {
        float4 v = *reinterpret_cast<const float4*>(src + i);
        bf16 o0 = (bf16)v.x, o1 = (bf16)v.y, o2 = (bf16)v.z, o3 = (bf16)v.w;
        u32 lo, hi;
        { union { bf16 h[2]; u32 u; } t; t.h[0]=o0; t.h[1]=o1; lo=t.u; }
        { union { bf16 h[2]; u32 u; } t; t.h[0]=o2; t.h[1]=o3; hi=t.u; }
        *reinterpret_cast<u32*>(dst + i) = lo;
        *reinterpret_cast<u32*>(dst + i + 2) = hi;
    }
}

// ---------------------------------------------------------------------------
// Stage slab rows [r0,+16) x [head(K1,cached-flag hc) | body(1024, flag bc)]
// into abuf[16][APITCH].
// ---------------------------------------------------------------------------
DEV void stage(bf16* abuf, int tid, int r0,
               const bf16* head, long hrs, int K1, bool hc,
               const bf16* body, long brs, bool bc)
{
    const int CHN = (K1 + CH) >> 3;
    const int TOT = 16 * CHN;
    for (int idx = tid; idx < TOT; idx += 512) {
        const int row = idx / CHN;
        const int k = (idx - row * CHN) * 8;
        bf16x8 v;
        if (k < K1) {
            const bf16* s = head + (long)(r0 + row) * hrs + k;
            v = hc ? ldfrag(s) : ld_act16(s);
        } else {
            const bf16* s = body + (long)(r0 + row) * brs + (k - K1);
            v = bc ? ldfrag(s) : ld_act16(s);
        }
        *reinterpret_cast<bf16x8*>(abuf + (long)row * APITCH + k) = v;
    }
    __syncthreads();
}

// ---------------------------------------------------------------------------
// GRU compute: 2 n-tiles/wave (32 e-cols), full K=[128|1024] from abuf.
// ---------------------------------------------------------------------------
DEV void gru2(const bf16* abuf, int r0, int colbase, int lane,
              const bf16* __restrict__ Wih, const bf16* __restrict__ Whh,
              const float* __restrict__ bih, const float* __restrict__ bhh,
              const float* __restrict__ efin, float* __restrict__ efout,
              bf16* __restrict__ ehout)
{
    const int lr = lane & 15, lkE = (lane >> 4) * 8;
    const bf16* arow = abuf + (long)lr * APITCH;
    f32x4 acc[2][4] = {};   // [tile][r,z,n_in,n_hh]

#pragma unroll 4
    for (int k = 0; k < CIN; k += 32) {
        bf16x8 a = *reinterpret_cast<const bf16x8*>(arow + k + lkE);
#pragma unroll
        for (int j = 0; j < 2; ++j) {
            const int c = colbase + j * 16 + lr;
#pragma unroll
            for (int g = 0; g < 3; ++g) {
                bf16x8 b = ldfrag(Wih + ((long)g * CH + c) * CIN + k + lkE);
                const int grp = (g == 2) ? 2 : g;
                acc[j][grp] = MFMA(a, b, acc[j][grp]);
            }
        }
    }
#pragma unroll 4
    for (int k = 0; k < CH; k += 32) {
        bf16x8 a = *reinterpret_cast<const bf16x8*>(arow + CIN + k + lkE);
#pragma unroll
        for (int j = 0; j < 2; ++j) {
            const int c = colbase + j * 16 + lr;
#pragma unroll
            for (int g = 0; g < 3; ++g) {
                bf16x8 b = ldfrag(Whh + ((long)g * CH + c) * CH + k + lkE);
                const int grp = (g == 2) ? 3 : g;
                acc[j][grp] = MFMA(a, b, acc[j][grp]);
            }
        }
    }
#pragma unroll
    for (int j = 0; j < 2; ++j) {
        const int c = colbase + j * 16 + lr;
        const float b0r = bih[c] + bhh[c];
        const float b0z = bih[CH + c] + bhh[CH + c];
        const float bin = bih[2 * CH + c];
        const float bhn = bhh[2 * CH + c];
#pragma unroll
        for (int i = 0; i < 4; ++i) {
            const int row = r0 + (lane >> 4) * 4 + i;
            float r = sigmoidf_(acc[j][0][i] + b0r);
            float u = sigmoidf_(acc[j][1][i] + b0z);
            float n = tanhf(acc[j][2][i] + bin + r * (acc[j][3][i] + bhn));
            float en = (1.0f - u) * n + u * efin[(long)row * CH + c];
            efout[(long)row * CH + c] = en;
            float vB = __shfl_xor(en, 1);
            if (!(lane & 1))
                sta4(ehout + (long)row * CH + c, pk2(en, vB));
        }
    }
}

// ---------------------------------------------------------------------------
// Linear: 4 n-tiles/wave (64 cols), K=Ktot from abuf; out row stride CD.
// ---------------------------------------------------------------------------
DEV void lin4(const bf16* abuf, int r0, int c0, int lane, int Ktot,
              const bf16* __restrict__ W, const float* __restrict__ bias,
              bf16* __restrict__ outb)
{
    const int lr = lane & 15, lkE = (lane >> 4) * 8;
    const bf16* arow = abuf + (long)lr * APITCH;
    f32x4 acc[4] = {};
#pragma unroll 4
    for (int k = 0; k < Ktot; k += 32) {
        bf16x8 a = *reinterpret_cast<const bf16x8*>(arow + k + lkE);
#pragma unroll
        for (int j = 0; j < 4; ++j) {
            const int c = c0 + j * 16 + lr;
            bf16x8 b = ldfrag(W + (long)c * Ktot + k + lkE);
            acc[j] = MFMA(a, b, acc[j]);
        }
    }
#pragma unroll
    for (int j = 0; j < 4; ++j) {
        const int c = c0 + j * 16 + lr;
        const float bb = bias[c];
#pragma unroll
        for (int i = 0; i < 4; ++i) {
            const int row = r0 + (lane >> 4) * 4 + i;
            float v = acc[j][i] + bb;
            float vB = __shfl_xor(v, 1);
            if (!(lane & 1))
                sta4(outb + (long)row * CD + c, pk2(v, vB));
        }
    }
}

// ---------------------------------------------------------------------------
// Head dot: 16 cols/wave, K=1024 from abuf.
// ---------------------------------------------------------------------------
DEV f32x4 head16(const bf16* abuf, int lane, int c2, const bf16* __restrict__ W)
{
    const int lr = lane & 15, lkE = (lane >> 4) * 8;
    const bf16* arow = abuf + (long)lr * APITCH;
    const bf16* wrow = W + (long)c2 * CD;
    f32x4 acc = {};
#pragma unroll 4
    for (int k = 0; k < CD; k += 32) {
        bf16x8 a = *reinterpret_cast<const bf16x8*>(arow + k + lkE);
        bf16x8 b = ldfrag(wrow + k + lkE);
        acc = MFMA(a, b, acc);
    }
    return acc;
}

// ---------------------------------------------------------------------------
// Planar flows + LGSSM on zbuf[16][128] (fp32, LDS); writes ztlg[t], zfl[t%4].
// ---------------------------------------------------------------------------
DEV void do_flows(const Prm& p, float* zbuf, int tid, int t, int slab)
{
    const int r = tid >> 5;            // 0..15
    const int c0 = (tid & 31) * 4;     // 0..124
    for (int kf = 0; kf < 3; ++kf) {
        float s0 = p.bp[kf * CZ + c0],     s1 = p.bp[kf * CZ + c0 + 1];
        float s2 = p.bp[kf * CZ + c0 + 2], s3 = p.bp[kf * CZ + c0 + 3];
        const float* w0 = p.Wp + ((long)kf * CZ + c0) * CZ;
#pragma unroll 8
        for (int j = 0; j < CZ; j += 4) {
            float4 z4 = *reinterpret_cast<const float4*>(&zbuf[r * CZ + j]);
            float4 a0 = *reinterpret_cast<const float4*>(w0 + j);
            float4 a1 = *reinterpret_cast<const float4*>(w0 + CZ + j);
            float4 a2 = *reinterpret_cast<const float4*>(w0 + 2 * CZ + j);
            float4 a3 = *reinterpret_cast<const float4*>(w0 + 3 * CZ + j);
            s0 += z4.x * a0.x + z4.y * a0.y + z4.z * a0.z + z4.w * a0.w;
            s1 += z4.x * a1.x + z4.y * a1.y + z4.z * a1.z + z4.w * a1.w;
            s2 += z4.x * a2.x + z4.y * a2.y + z4.z * a2.z + z4.w * a2.w;
            s3 += z4.x * a3.x + z4.y * a3.y + z4.z * a3.z + z4.w * a3.w;
        }
        const float uk = p.up[kf];
        __syncthreads();
        zbuf[r * CZ + c0]     += uk * tanhf(s0);
        zbuf[r * CZ + c0 + 1] += uk * tanhf(s1);
        zbuf[r * CZ + c0 + 2] += uk * tanhf(s2);
        zbuf[r * CZ + c0 + 3] += uk * tanhf(s3);
        __syncthreads();
    }
    // zt = z @ Wlg^T + blg
    float s0 = p.blg[c0], s1 = p.blg[c0 + 1], s2 = p.blg[c0 + 2], s3 = p.blg[c0 + 3];
    const float* w0 = p.Wlg + (long)c0 * CZ;
#pragma unroll 8
    for (int j = 0; j < CZ; j += 4) {
        float4 z4 = *reinterpret_cast<const float4*>(&zbuf[r * CZ + j]);
        float4 a0 = *reinterpret_cast<const float4*>(w0 + j);
        float4 a1 = *reinterpret_cast<const float4*>(w0 + CZ + j);
        float4 a2 = *reinterpret_cast<const float4*>(w0 + 2 * CZ + j);
        float4 a3 = *reinterpret_cast<const float4*>(w0 + 3 * CZ + j);
        s0 += z4.x * a0.x + z4.y * a0.y + z4.z * a0.z + z4.w * a0.w;
        s1 += z4.x * a1.x + z4.y * a1.y + z4.z * a1.z + z4.w * a1.w;
        s2 += z4.x * a2.x + z4.y * a2.y + z4.z * a2.z + z4.w * a2.w;
        s3 += z4.x * a3.x + z4.y * a3.y + z4.z * a3.z + z4.w * a3.w;
    }
    const int grow = slab * 16 + r;
    bf16* zt = p.ztlg + ((size_t)t * CB + grow) * CZ + c0;
    sta4(zt,     pk2(s0, s1));
    sta4(zt + 2, pk2(s2, s3));
    bf16* zf = p.zfl + ((size_t)(t & 3) * CB + grow) * CZ + c0;
    sta4(zf,     pk2(zbuf[r * CZ + c0],     zbuf[r * CZ + c0 + 1]));
    sta4(zf + 2, pk2(zbuf[r * CZ + c0 + 2], zbuf[r * CZ + c0 + 3]));
}

// ---------------------------------------------------------------------------
// GRU role (QG / PG).
// ---------------------------------------------------------------------------
DEV void run_gru_role(const Prm& p, bf16* abuf, int slab, int slice,
                      const bf16* headbase, long hstep, long hrs,
                      const bf16* Wih, const bf16* Whh,
                      const float* bih, const float* bhh,
                      float* efm, bf16* hist, int fSelf,
                      int w4f, int w4o, int w5f, int w5o, int w6f, int w6o)
{
    const int tid = threadIdx.x, lane = tid & 63, wave = tid >> 6;
    const int r0 = slab * 16;
    const int colbase = slice * 256 + wave * 32;
    u32* F = p.F;
    const int DEm = p.DEm;
    const bool big = p.big != 0;

    for (int t = 0; t < CW; ++t) {
        if (tid < 4)       poll_ge(F + (fSelf + slab * 4 + tid) * FS, t);
        else if (tid == 4) poll_ge(F + w4f * FS, t + w4o);
        else if (tid == 5 && w5f >= 0) poll_ge(F + w5f * FS, t + w5o);
        else if (tid == 6 && w6f >= 0) poll_ge(F + w6f * FS, t + w6o);
        __syncthreads();

        stage(abuf, tid, r0, headbase + (long)t * hstep, hrs, CIN, true,
              hist + (size_t)((t - 1) & DEm) * CB * CH, CH, big);

        gru2(abuf, r0, colbase, lane, Wih, Whh, bih, bhh,
             efm + (size_t)(t & 1) * CB * CH,
             efm + (size_t)((t & 1) ^ 1) * CB * CH,
             hist + (size_t)(t & DEm) * CB * CH);

        asm volatile("s_waitcnt vmcnt(0)" ::: "memory");
        __syncthreads();
        if (tid == 0) sta4(F + (fSelf + slab * 4 + slice) * FS, (u32)(t + 1));
    }
}

// ---------------------------------------------------------------------------
// Aux role (QA / PA): lin half + head + (Q: reparam/flows | P: output).
// ---------------------------------------------------------------------------
DEV void run_aux_role(const Prm& p, bf16* abuf, float* zbuf,
                      int slab, int half, bool isQ)
{
    const int tid = threadIdx.x, lane = tid & 63, wave = tid >> 6;
    const int r0 = slab * 16;
    const int c2 = wave * 16 + (lane & 15);
    u32* F = p.F;
    const int DEm = p.DEm;
    const bool big = p.big != 0;

    const int fG  = isQ ? FQG : FPG;
    const int fD  = (isQ ? FQAd : FPAd) + slab * 2;
    const int fB  = (isQ ? FQAb : FPAb) + slab;
    const int fA  = (isQ ? FQAa : FPAa) + slab;
    const bf16* Wlin = isQ ? p.Wd_qb : p.Wd_pb;
    const int   Klin = isQ ? (CZ + CH) : CH;
    const float* blin = isQ ? p.bd_q : p.bd_p;
    bf16* dv = isQ ? p.dvpp : p.ddvpp;
    float* sh = isQ ? p.shq : p.shp;
    const bf16* Wmu = isQ ? p.Wmu_qb : p.Wmu_pb;
    const bf16* Wsg = isQ ? p.Wsg_qb : p.Wsg_pb;
    const bf16* hist = isQ ? p.e_h : p.d_h;

    for (int t = 0; t < CW; ++t) {
        if (tid < 4)              poll_ge(F + (fG + slab * 4 + tid) * FS, t + 1);
        else if (tid == 4 && isQ) poll_ge(F + fA * FS, t);
        __syncthreads();

        if (isQ)
            stage(abuf, tid, r0, p.zfl + (size_t)((t - 1) & 3) * CB * CZ, CZ, CZ, false,
                  hist + (size_t)(t & DEm) * CB * CH, CH, big);
        else
            stage(abuf, tid, r0, nullptr, 0, 0, false,
                  hist + (size_t)(t & DEm) * CB * CH, CH, big);

        lin4(abuf, r0, half * 512 + wave * 64, lane, Klin, Wlin, blin,
             dv + (size_t)(t & 1) * CB * CD);
        asm volatile("s_waitcnt vmcnt(0)" ::: "memory");
        __syncthreads();
        if (tid == 0) {
            sta4(F + (fD + half) * FS, (u32)(t + 1));
            poll_ge(F + (fD + (half ^ 1)) * FS, t + 1);
        }
        __syncthreads();

        stage(abuf, tid, r0, nullptr, 0, 0, false,
              dv + (size_t)(t & 1) * CB * CD, CD, false);

        if (half == 1) {
            f32x4 vs = head16(abuf, lane, c2, Wsg);
            float* shw = sh + (size_t)(t & 1) * CB * CZ;
#pragma unroll
            for (int i = 0; i < 4; ++i) {
                const int row = r0 + (lane >> 4) * 4 + i;
                sta4(shw + (size_t)row * CZ + c2, __float_as_uint(vs[i]));
            }
            asm volatile("s_waitcnt vmcnt(0)" ::: "memory");
            __syncthreads();
            if (tid == 0) sta4(F + fB * FS, (u32)(t + 1));
        } else {
            f32x4 vm = head16(abuf, lane, c2, Wmu);
            if (tid == 0) poll_ge(F + fB * FS, t + 1);
            __syncthreads();
            const float* shr = sh + (size_t)(t & 1) * CB * CZ;
#pragma unroll
            for (int i = 0; i < 4; ++i) {
                const int row = r0 + (lane >> 4) * 4 + i;
                float vs = __uint_as_float(lda4(shr + (size_t)row * CZ + c2));
                if (isQ) {
                    float mu = vm[i] + p.bmu_q[c2];
                    float lv = softplusf_(vs + p.bsig_q[c2]);
                    float e  = p.eps_q[(size_t)row * CW * CZ + (size_t)t * CZ + c2];
                    float z  = mu + expf(0.5f * lv) * e;
                    p.out_mu[(size_t)row * CW * CZ + (size_t)t * CZ + c2] = mu;
                    p.out_lv[(size_t)row * CW * CZ + (size_t)t * CZ + c2] = lv;
                    zbuf[((lane >> 4) * 4 + i) * CZ + c2] = z;
                } else {
                    float m  = vm[i] + p.bmu_p[c2];
                    float sg = softplusf_(vs + p.bsig_p[c2]);
                    float e  = p.eps_p[(size_t)row * CW * COUT + (size_t)t * COUT + c2];
                    p.out_o[(size_t)row * CW * COUT + (size_t)t * COUT + c2] = m + sg * e;
                }
            }
            if (isQ) {
                __syncthreads();
                do_flows(p, zbuf, tid, t, slab);
            }
            asm volatile("s_waitcnt vmcnt(0)" ::: "memory");
            __syncthreads();
            if (tid == 0) sta4(F + fA * FS, (u32)(t + 1));
        }
    }
}

// ---------------------------------------------------------------------------
__launch_bounds__(512)
__global__ void mega(Prm p)
{
    __shared__ bf16  abuf[16 * APITCH];
    __shared__ float zbuf[16 * CZ];
    const int wg = blockIdx.x;

    if (wg < 64) {
        const int slab = wg >> 2, slice = wg & 3;
        run_gru_role(p, abuf, slab, slice,
                     p.x_b, (long)CIN, (long)CW * CIN,
                     p.Wih_qb, p.Whh_qb, p.bih_q, p.bhh_q,
                     p.ef, p.e_h, FQG,
                     FQAa + slab, -3, FQAb + slab, -3, -1, 0);
    } else if (wg < 96) {
        run_aux_role(p, abuf, zbuf, (wg - 64) >> 1, (wg - 64) & 1, true);
    } else if (wg < 160) {
        const int slab = (wg - 96) >> 2, slice = (wg - 96) & 3;
        run_gru_role(p, abuf, slab, slice,
                     p.ztlg, (long)CB * CZ, (long)CZ,
                     p.Wih_pb, p.Whh_pb, p.bih_p, p.bhh_p,
                     p.df, p.d_h, FPG,
                     FQAa + slab, +1, FPAa + slab, -3, FPAb + slab, -3);
    } else {
        run_aux_role(p, abuf, zbuf, (wg - 160) >> 1, (wg - 160) & 1, false);
    }
}

// ---------------------------------------------------------------------------
// Host driver
// ---------------------------------------------------------------------------
extern "C" void kernel_launch(void* const* d_in, const int* in_sizes, int n_in,
                              void* d_out, int out_size, void* d_ws, size_t ws_size,
                              hipStream_t stream)
{
    Prm p;
    const float* x      = (const float*)d_in[0];
    p.eps_q  = (const float*)d_in[1];
    p.eps_p  = (const float*)d_in[2];
    const float* Wih_q  = (const float*)d_in[3];
    const float* Whh_q  = (const float*)d_in[4];
    p.bih_q  = (const float*)d_in[5];
    p.bhh_q  = (const float*)d_in[6];
    const float* Wd_q   = (const float*)d_in[7];
    p.bd_q   = (const float*)d_in[8];
    const float* Wmu_q  = (const float*)d_in[9];
    p.bmu_q  = (const float*)d_in[10];
    const float* Wsig_q = (const float*)d_in[11];
    p.bsig_q = (const float*)d_in[12];
    p.Wp     = (const float*)d_in[13];
    p.bp     = (const float*)d_in[14];
    p.up     = (const float*)d_in[15];
    p.Wlg    = (const float*)d_in[16];
    p.blg    = (const float*)d_in[17];
    const float* Wih_p  = (const float*)d_in[18];
    const float* Whh_p  = (const float*)d_in[19];
    p.bih_p  = (const float*)d_in[20];
    p.bhh_p  = (const float*)d_in[21];
    const float* Wd_p   = (const float*)d_in[22];
    p.bd_p   = (const float*)d_in[23];
    const float* Wmu_p  = (const float*)d_in[24];
    p.bmu_p  = (const float*)d_in[25];
    const float* Wsig_p = (const float*)d_in[26];
    p.bsig_p = (const float*)d_in[27];

    p.out_o  = (float*)d_out;
    p.out_mu = p.out_o + (size_t)CB * CW * COUT;
    p.out_lv = p.out_mu + (size_t)CB * CW * CZ;

    // mode select
    const int DE = (ws_size >= (size_t)200 * 1024 * 1024) ? 128 : 4;
    p.DEm = DE - 1;
    p.big = (DE == 128) ? 1 : 0;

    char* wp_ = (char*)d_ws;
    auto carve = [&](size_t bytes) -> void* {
        void* q = (void*)wp_;
        wp_ += (bytes + 255) & ~(size_t)255;
        return q;
    };
    p.ef    = (float*)carve((size_t)2 * CB * CH * 4);
    p.df    = (float*)carve((size_t)2 * CB * CH * 4);
    p.e_h   = (bf16*)carve((size_t)DE * CB * CH * 2);
    p.d_h   = (bf16*)carve((size_t)DE * CB * CH * 2);
    p.dvpp  = (bf16*)carve((size_t)2 * CB * CD * 2);
    p.ddvpp = (bf16*)carve((size_t)2 * CB * CD * 2);
    p.ztlg  = (bf16*)carve((size_t)CW * CB * CZ * 2);
    p.zfl   = (bf16*)carve((size_t)4 * CB * CZ * 2);
    p.shq   = (float*)carve((size_t)2 * CB * CZ * 4);
    p.shp   = (float*)carve((size_t)2 * CB * CZ * 4);
    p.F     = (u32*)carve((size_t)NFLAG * FS * 4);
    bf16* x_b    = (bf16*)carve((size_t)CB * CW * CIN * 2);
    bf16* Wih_qb = (bf16*)carve((size_t)3 * CH * CIN * 2);
    bf16* Whh_qb = (bf16*)carve((size_t)3 * CH * CH * 2);
    bf16* Wd_qb  = (bf16*)carve((size_t)CD * (CZ + CH) * 2);
    bf16* Wmu_qb = (bf16*)carve((size_t)CZ * CD * 2);
    bf16* Wsg_qb = (bf16*)carve((size_t)CZ * CD * 2);
    bf16* Wih_pb = (bf16*)carve((size_t)3 * CH * CZ * 2);
    bf16* Whh_pb = (bf16*)carve((size_t)3 * CH * CH * 2);
    bf16* Wd_pb  = (bf16*)carve((size_t)CD * CH * 2);
    bf16* Wmu_pb = (bf16*)carve((size_t)COUT * CD * 2);
    bf16* Wsg_pb = (bf16*)carve((size_t)COUT * CD * 2);
    p.x_b = x_b;       p.Wih_qb = Wih_qb; p.Whh_qb = Whh_qb;
    p.Wd_qb = Wd_qb;   p.Wmu_qb = Wmu_qb; p.Wsg_qb = Wsg_qb;
    p.Wih_pb = Wih_pb; p.Whh_pb = Whh_pb; p.Wd_pb = Wd_pb;
    p.Wmu_pb = Wmu_pb; p.Wsg_pb = Wsg_pb;

    // zero-init: master slot0, history slot DE-1 (e(-1)=d(-1)=0), zfl, flags
    hipMemsetAsync(p.ef, 0, (size_t)CB * CH * 4, stream);
    hipMemsetAsync(p.df, 0, (size_t)CB * CH * 4, stream);
    hipMemsetAsync(p.e_h + (size_t)(DE - 1) * CB * CH, 0, (size_t)CB * CH * 2, stream);
    hipMemsetAsync(p.d_h + (size_t)(DE - 1) * CB * CH, 0, (size_t)CB * CH * 2, stream);
    hipMemsetAsync(p.zfl, 0, (size_t)4 * CB * CZ * 2, stream);
    hipMemsetAsync(p.F, 0, (size_t)NFLAG * FS * 4, stream);

    auto cvt = [&](const float* s, bf16* d, size_t n) {
        k_cvt<<<dim3((unsigned)((n / 4 + 255) / 256)), dim3(256), 0, stream>>>(s, d, (int)n);
    };
    cvt(x,      x_b,    (size_t)CB * CW * CIN);
    cvt(Wih_q,  Wih_qb, (size_t)3 * CH * CIN);
    cvt(Whh_q,  Whh_qb, (size_t)3 * CH * CH);
    cvt(Wd_q,   Wd_qb,  (size_t)CD * (CZ + CH));
    cvt(Wmu_q,  Wmu_qb, (size_t)CZ * CD);
    cvt(Wsig_q, Wsg_qb, (size_t)CZ * CD);
    cvt(Wih_p,  Wih_pb, (size_t)3 * CH * CZ);
    cvt(Whh_p,  Whh_pb, (size_t)3 * CH * CH);
    cvt(Wd_p,   Wd_pb,  (size_t)CD * CH);
    cvt(Wmu_p,  Wmu_pb, (size_t)COUT * CD);
    cvt(Wsig_p, Wsg_pb, (size_t)COUT * CD);

    mega<<<dim3(192), dim3(512), 0, stream>>>(p);
}